// Round 24
// baseline (122.087 us; speedup 1.0000x reference)
//
#include <hip/hip_runtime.h>

typedef __attribute__((ext_vector_type(8))) short bf16x8;
typedef __attribute__((ext_vector_type(4))) float f32x4;
typedef __attribute__((ext_vector_type(16))) float f32x16;

typedef const __attribute__((address_space(1))) unsigned int gu32;
typedef __attribute__((address_space(3))) unsigned int lu32;

__device__ __forceinline__ void async16(const void* g, void* l) {
  __builtin_amdgcn_global_load_lds((gu32*)g, (lu32*)l, 16, 0, 0);
}

__device__ __forceinline__ unsigned short f2bf(float f) {
  unsigned int u = __float_as_uint(f);
  u += 0x7fffu + ((u >> 16) & 1u);
  return (unsigned short)(u >> 16);
}
__device__ __forceinline__ float b2f(unsigned short s) {
  return __uint_as_float(((unsigned int)s) << 16);
}
__device__ __forceinline__ unsigned int cvtpk(float lo, float hi) {
  unsigned int w;
  asm("v_cvt_pk_bf16_f32 %0, %1, %2" : "=v"(w) : "v"(lo), "v"(hi));
  return w;
}
__device__ __forceinline__ void plswap(unsigned int& x, unsigned int& y) {
  asm("v_permlane32_swap_b32 %0, %1" : "+v"(x), "+v"(y));
}
__device__ __forceinline__ float max3f(float a, float b, float c) {
  float d;
  asm("v_max3_f32 %0, %1, %2, %3" : "=v"(d) : "v"(a), "v"(b), "v"(c));
  return d;
}

// ---------------- all fp32 -> bf16 conversions in one launch ----------------
__global__ __launch_bounds__(256) void cvt_all(const float* __restrict__ x,
                                               const float* __restrict__ Wq,
                                               const float* __restrict__ Wk,
                                               const float* __restrict__ Wv,
                                               const float* __restrict__ Wo,
                                               unsigned short* __restrict__ xb,
                                               unsigned short* __restrict__ Wb,
                                               unsigned short* __restrict__ Wob) {
  int i = blockIdx.x * 256 + threadIdx.x;
  const float* src;
  unsigned short* dst;
  int j;
  if (i < (1 << 20)) {
    src = x; dst = xb; j = i;
  } else {
    int k = i - (1 << 20);
    int wsel = k >> 18;
    j = k & 0x3FFFF;
    src = (wsel == 0) ? Wq : (wsel == 1) ? Wk : (wsel == 2) ? Wv : Wo;
    dst = (wsel == 0) ? Wb : (wsel == 1) ? Wb + (1 << 20)
        : (wsel == 2) ? Wb + (2 << 20) : Wob;
  }
  float4 v = ((const float4*)src)[j];
  ushort4 o;
  o.x = f2bf(v.x); o.y = f2bf(v.y); o.z = f2bf(v.z); o.w = f2bf(v.w);
  ((ushort4*)dst)[j] = o;
}

// ---------------- QKV GEMM (R15, unchanged) ----------------
template <int WRITE_F32>
__global__ __launch_bounds__(256) void gemm_bt(const unsigned short* __restrict__ A,
                                               const unsigned short* __restrict__ B,
                                               void* __restrict__ Cp, int N, int K) {
  __shared__ __align__(16) unsigned short Al[3][128 * 32];
  __shared__ __align__(16) unsigned short Bl[3][128 * 32];
  const int t = threadIdx.x;
  const int w = t >> 6, l = t & 63;
  const int wm = w >> 1, wn = w & 1;
  const int lr = l & 15, lg = l >> 4;
  const long bm = (long)blockIdx.x * 128, bn = (long)blockIdx.y * 128;
  const int srow = t >> 2;
  const int c8 = t & 3;
  const int KT = K >> 5;
  f32x4 acc[4][4] = {};

  auto STAGE = [&](int ts) {
    const int bi = ts % 3;
    const int k0 = ts * 32;
    #pragma unroll
    for (int r = 0; r < 2; ++r) {
      int row = r * 64 + srow;
      async16(&A[(bm + row) * (long)K + k0 + c8 * 8], &Al[bi][row * 32 + c8 * 8]);
      async16(&B[(bn + row) * (long)K + k0 + c8 * 8], &Bl[bi][row * 32 + c8 * 8]);
    }
  };

  STAGE(0);
  STAGE(1);
  for (int kt = 0; kt < KT; ++kt) {
    const int cur = kt % 3;
    if (kt < KT - 1) asm volatile("s_waitcnt vmcnt(4)" ::: "memory");
    else             asm volatile("s_waitcnt vmcnt(0)" ::: "memory");
    __builtin_amdgcn_s_barrier();
    __builtin_amdgcn_sched_barrier(0);
    if (kt + 2 < KT) STAGE(kt + 2);
    bf16x8 af[4], bf[4];
    #pragma unroll
    for (int i = 0; i < 4; ++i) {
      af[i] = *(const bf16x8*)&Al[cur][(wm * 64 + i * 16 + lr) * 32 + lg * 8];
      bf[i] = *(const bf16x8*)&Bl[cur][(wn * 64 + i * 16 + lr) * 32 + lg * 8];
    }
    #pragma unroll
    for (int i = 0; i < 4; ++i)
      #pragma unroll
      for (int j = 0; j < 4; ++j)
        acc[i][j] = __builtin_amdgcn_mfma_f32_16x16x32_bf16(af[i], bf[j], acc[i][j], 0, 0, 0);
  }
  #pragma unroll
  for (int i = 0; i < 4; ++i)
    #pragma unroll
    for (int j = 0; j < 4; ++j)
      #pragma unroll
      for (int r = 0; r < 4; ++r) {
        long row = bm + wm * 64 + i * 16 + lg * 4 + r;
        long col = bn + wn * 64 + j * 16 + lr;
        float v = acc[i][j][r];
        if (WRITE_F32) ((float*)Cp)[row * N + col] = v;
        else ((unsigned short*)Cp)[row * N + col] = f2bf(v);
      }
}

// ---------------- proj GEMM (R16, unchanged) ----------------
__global__ __launch_bounds__(128) void gemm2_bt(const unsigned short* __restrict__ A,
                                                const unsigned short* __restrict__ B,
                                                float* __restrict__ Cp, int N, int K) {
  __shared__ __align__(16) unsigned short Al[3][64 * 32];
  __shared__ __align__(16) unsigned short Bl[3][128 * 32];
  const int t = threadIdx.x;
  const int w = t >> 6, l = t & 63;
  const int lr = l & 15, lg = l >> 4;
  const long bm = (long)blockIdx.x * 64, bn = (long)blockIdx.y * 128;
  const int KT = K >> 5;
  f32x4 acc[4][4] = {};

  auto STAGE = [&](int ts) {
    const int bi = ts % 3;
    const int k0 = ts * 32;
    #pragma unroll
    for (int r = 0; r < 2; ++r) {
      int u = r * 128 + 64 * w + l;
      int row = u >> 2, c8 = u & 3;
      async16(&A[(bm + row) * (long)K + k0 + c8 * 8], &Al[bi][row * 32 + c8 * 8]);
    }
    #pragma unroll
    for (int r = 0; r < 4; ++r) {
      int u = r * 128 + 64 * w + l;
      int row = u >> 2, c8 = u & 3;
      async16(&B[(bn + row) * (long)K + k0 + c8 * 8], &Bl[bi][row * 32 + c8 * 8]);
    }
  };

  STAGE(0);
  STAGE(1);
  for (int kt = 0; kt < KT; ++kt) {
    const int cur = kt % 3;
    if (kt < KT - 1) asm volatile("s_waitcnt vmcnt(6)" ::: "memory");
    else             asm volatile("s_waitcnt vmcnt(0)" ::: "memory");
    __builtin_amdgcn_s_barrier();
    __builtin_amdgcn_sched_barrier(0);
    if (kt + 2 < KT) STAGE(kt + 2);
    bf16x8 af[4], bf[4];
    #pragma unroll
    for (int i = 0; i < 4; ++i) {
      af[i] = *(const bf16x8*)&Al[cur][(i * 16 + lr) * 32 + lg * 8];
      bf[i] = *(const bf16x8*)&Bl[cur][(w * 64 + i * 16 + lr) * 32 + lg * 8];
    }
    #pragma unroll
    for (int i = 0; i < 4; ++i)
      #pragma unroll
      for (int j = 0; j < 4; ++j)
        acc[i][j] = __builtin_amdgcn_mfma_f32_16x16x32_bf16(af[i], bf[j], acc[i][j], 0, 0, 0);
  }
  #pragma unroll
  for (int i = 0; i < 4; ++i)
    #pragma unroll
    for (int j = 0; j < 4; ++j)
      #pragma unroll
      for (int r = 0; r < 4; ++r) {
        long row = bm + i * 16 + lg * 4 + r;
        long col = bn + w * 64 + j * 16 + lr;
        Cp[row * N + col] = acc[i][j][r];
      }
}

// ---------------- fused RoPE (Q,K) + V-transpose (R16, unchanged) ----------
__global__ __launch_bounds__(256) void ropevtr_k(unsigned short* __restrict__ QKV,
                                                 unsigned short* __restrict__ Vt) {
  __shared__ unsigned short tl[64][66];
  const int bx = blockIdx.x;
  const int t = threadIdx.x;
  if (bx < 4096) {
    float* csl = (float*)&tl[0][0];
    float* snl = csl + 32;
    const int row = bx;
    const int s = row & 2047;
    if (t < 32) {
      float invf = exp2f((float)t * (-13.287712379549449f / 32.0f));
      float sn, cs;
      sincosf((float)s * invf, &sn, &cs);
      csl[t] = cs; snl[t] = sn;
    }
    __syncthreads();
    const int col0 = (t < 128) ? t * 8 : 1024 + (t - 128) * 8;
    const int i0 = (t & 7) * 4;
    unsigned short* p = &QKV[(size_t)row * 3072 + col0];
    bf16x8 v = *(const bf16x8*)p;
    bf16x8 o;
    #pragma unroll
    for (int j = 0; j < 4; ++j) {
      float x1 = b2f((unsigned short)v[2 * j]);
      float x2 = b2f((unsigned short)v[2 * j + 1]);
      float cs = csl[i0 + j], sn = snl[i0 + j];
      o[2 * j]     = (short)f2bf(x1 * cs - x2 * sn);
      o[2 * j + 1] = (short)f2bf(x1 * sn + x2 * cs);
    }
    *(bf16x8*)p = o;
  } else {
    const int idx = bx - 4096;
    const int kt = idx & 31;
    const int bh = idx >> 5;
    const int b = bh >> 4, h = bh & 15;
    const int row = t >> 3, c8 = t & 7;
    #pragma unroll
    for (int r = 0; r < 2; ++r) {
      int k = r * 32 + row;
      bf16x8 v = *(const bf16x8*)&QKV[((long)b * 2048 + kt * 64 + k) * 3072 + 2048 + h * 64 + c8 * 8];
      #pragma unroll
      for (int j = 0; j < 8; ++j) tl[c8 * 8 + j][k] = (unsigned short)v[j];
    }
    __syncthreads();
    #pragma unroll
    for (int r = 0; r < 2; ++r) {
      int d = r * 32 + row;
      ushort4 a, bq;
      a.x = tl[d][c8 * 8 + 0]; a.y = tl[d][c8 * 8 + 1];
      a.z = tl[d][c8 * 8 + 2]; a.w = tl[d][c8 * 8 + 3];
      bq.x = tl[d][c8 * 8 + 4]; bq.y = tl[d][c8 * 8 + 5];
      bq.z = tl[d][c8 * 8 + 6]; bq.w = tl[d][c8 * 8 + 7];
      long off = ((long)bh * 64 + d) * 2048 + kt * 64 + c8 * 8;
      *(ushort4*)&Vt[off] = a;
      *(ushort4*)&Vt[off + 4] = bq;
    }
  }
}

// ---------------- causal flash attention: 128 KV rows per step (R17) -------
// One barrier + vmcnt drain + mask/max/rescale sequence per TWO 64-row KV
// tiles. QK = 4 independent 4-deep MFMA chains; 64 exps batched. Mask rule:
// tile kt >= ktmax -> apply triangle (kt > ktmax wipes the tile entirely),
// so all waves run all steps uniformly. V stays LDS-staged (R22's V-direct
// regressed 47->72 us: load latency landed on the PV MFMA chain).
__global__ __launch_bounds__(256) void attn_k(const unsigned short* __restrict__ QKV,
                                              const unsigned short* __restrict__ VtG,
                                              unsigned short* __restrict__ O) {
  __shared__ __align__(16) unsigned short Kl[2][2][64 * 64];
  __shared__ __align__(16) unsigned short Vl[2][2][64 * 64];
  const int t = threadIdx.x;
  const int w = t >> 6, l = t & 63;
  const int q31 = l & 31, hi = l >> 5;
  const int bh = blockIdx.x;               // same head -> same XCD
  const int y = (int)blockIdx.y;
  const int qt = (y < 8) ? (15 - y) : (y - 8);
  const int b = bh >> 4, h = bh & 15;
  const int Qb = qt * 128;
  const long rowb = (long)b * 2048;
  const int L = 3072;
  const int NTS = qt + 1;                  // steps of 128 KV rows
  const float cexp = 0.125f * 1.4426950408889634f;

  const int qmy = Qb + 32 * w + q31;
  const long qgrow = rowb + qmy;
  const int ktmax = (Qb + 32 * w) >> 6;    // wave-uniform diagonal tile

  bf16x8 qf[4];
  #pragma unroll
  for (int dk = 0; dk < 4; ++dk)
    qf[dk] = *(const bf16x8*)&QKV[qgrow * L + h * 64 + dk * 16 + hi * 8];

  bf16x8 onesf;
  #pragma unroll
  for (int j = 0; j < 8; ++j) onesf[j] = (short)0x3F80;

  float m_ = -1e30f;
  f32x16 oa[2], la;
  #pragma unroll
  for (int r = 0; r < 16; ++r) { oa[0][r] = 0.0f; oa[1][r] = 0.0f; la[r] = 0.0f; }

  auto STAGE2 = [&](int ts) {   // 8 async16/thread: 2 tiles x (2 K + 2 V)
    const int bi = ts & 1;
    const long vrowb = (long)bh * 64;
    #pragma unroll
    for (int s = 0; s < 2; ++s) {
      const int kt = 2 * ts + s;
      const long kb = rowb + (long)kt * 64;
      #pragma unroll
      for (int r = 0; r < 2; ++r) {
        int row = w * 16 + r * 8 + (l >> 3);
        int c8s = ((l & 7) ^ (row & 7)) * 8;
        async16(&QKV[(kb + row) * L + 1024 + h * 64 + c8s], &Kl[bi][s][row * 64 + (l & 7) * 8]);
        async16(&VtG[(vrowb + row) * 2048 + kt * 64 + c8s], &Vl[bi][s][row * 64 + (l & 7) * 8]);
      }
    }
  };

  STAGE2(0);

  for (int ts = 0; ts < NTS; ++ts) {
    const int bi = ts & 1;
    asm volatile("s_waitcnt vmcnt(0)" ::: "memory");   // STAGE2(ts) landed
    __builtin_amdgcn_s_barrier();                      // prev step's readers done
    __builtin_amdgcn_sched_barrier(0);
    if (ts + 1 < NTS) STAGE2(ts + 1);

    // ---- S^T for both tiles: 4 independent 4-deep MFMA chains ----
    f32x16 st[2][2];
    #pragma unroll
    for (int s = 0; s < 2; ++s)
      #pragma unroll
      for (int kt2 = 0; kt2 < 2; ++kt2)
        #pragma unroll
        for (int r = 0; r < 16; ++r) st[s][kt2][r] = 0.0f;
    __builtin_amdgcn_s_setprio(1);
    #pragma unroll
    for (int dk = 0; dk < 4; ++dk)
      #pragma unroll
      for (int s = 0; s < 2; ++s)
        #pragma unroll
        for (int kt2 = 0; kt2 < 2; ++kt2) {
          int krow = kt2 * 32 + q31;
          bf16x8 kfr = *(const bf16x8*)&Kl[bi][s][krow * 64 + (((2 * dk + hi) ^ (krow & 7)) * 8)];
          st[s][kt2] = __builtin_amdgcn_mfma_f32_32x32x16_bf16(kfr, qf[dk], st[s][kt2], 0, 0, 0);
        }
    __builtin_amdgcn_s_setprio(0);
    // ---- causal mask: tile kt >= ktmax (kt > ktmax wipes fully) ----
    #pragma unroll
    for (int s = 0; s < 2; ++s) {
      int kt = 2 * ts + s;
      if (kt >= ktmax) {
        #pragma unroll
        for (int kt2 = 0; kt2 < 2; ++kt2)
          #pragma unroll
          for (int r = 0; r < 16; ++r) {
            int kg = kt * 64 + kt2 * 32 + (r & 3) + 8 * (r >> 2) + 4 * hi;
            if (kg > qmy) st[s][kt2][r] = -1e30f;
          }
      }
    }
    // ---- online softmax over 128 cols, one sequence per step ----
    float m0[8];
    #pragma unroll
    for (int i = 0; i < 8; ++i)
      m0[i] = fmaxf(fmaxf(max3f(st[0][0][i], st[0][0][i + 8], st[0][1][i]),
                          max3f(st[0][1][i + 8], st[1][0][i], st[1][0][i + 8])),
                    fmaxf(st[1][1][i], st[1][1][i + 8]));
    float mt = max3f(max3f(m0[0], m0[1], m0[2]), max3f(m0[3], m0[4], m0[5]),
                     fmaxf(m0[6], m0[7]));
    if (__any((mt - m_) * cexp > 8.0f)) {   // defer-max (T13)
      float mg = fmaxf(mt, __shfl_xor(mt, 32, 64));
      float mn = fmaxf(m_, mg);
      float al = __builtin_amdgcn_exp2f((m_ - mn) * cexp);
      m_ = mn;
      la[0] *= al;
      #pragma unroll
      for (int dt = 0; dt < 2; ++dt)
        #pragma unroll
        for (int r = 0; r < 16; ++r) oa[dt][r] *= al;
    }
    const float mc = m_ * cexp;
    #pragma unroll
    for (int s = 0; s < 2; ++s)
      #pragma unroll
      for (int kt2 = 0; kt2 < 2; ++kt2)
        #pragma unroll
        for (int r = 0; r < 16; ++r)
          st[s][kt2][r] = __builtin_amdgcn_exp2f(fmaf(st[s][kt2][r], cexp, -mc));
    // ---- per tile: pack P, then PV + l on the matrix pipe ----
    #pragma unroll
    for (int s = 0; s < 2; ++s) {
      bf16x8 pfr[4];
      #pragma unroll
      for (int ks = 0; ks < 4; ++ks) {
        int tt = ks >> 1, gX = 2 * (ks & 1), gY = gX + 1;
        unsigned int x1 = cvtpk(st[s][tt][4 * gX + 0], st[s][tt][4 * gX + 1]);
        unsigned int y1 = cvtpk(st[s][tt][4 * gY + 0], st[s][tt][4 * gY + 1]);
        plswap(x1, y1);
        unsigned int x2 = cvtpk(st[s][tt][4 * gX + 2], st[s][tt][4 * gX + 3]);
        unsigned int y2 = cvtpk(st[s][tt][4 * gY + 2], st[s][tt][4 * gY + 3]);
        plswap(x2, y2);
        union { unsigned int u[4]; bf16x8 b; } cc;
        cc.u[0] = x1; cc.u[1] = x2; cc.u[2] = y1; cc.u[3] = y2;
        pfr[ks] = cc.b;
      }
      __builtin_amdgcn_s_setprio(1);
      #pragma unroll
      for (int ks = 0; ks < 4; ++ks) {
        la = __builtin_amdgcn_mfma_f32_32x32x16_bf16(onesf, pfr[ks], la, 0, 0, 0);
        #pragma unroll
        for (int dt = 0; dt < 2; ++dt) {
          int vrow = dt * 32 + q31;
          bf16x8 vf = *(const bf16x8*)&Vl[bi][s][vrow * 64 + (((2 * ks + hi) ^ (vrow & 7)) * 8)];
          oa[dt] = __builtin_amdgcn_mfma_f32_32x32x16_bf16(vf, pfr[ks], oa[dt], 0, 0, 0);
        }
      }
      __builtin_amdgcn_s_setprio(0);
    }
  }

  float inv = 1.0f / la[0];
  #pragma unroll
  for (int dt = 0; dt < 2; ++dt)
    #pragma unroll
    for (int g = 0; g < 4; ++g) {
      ushort4 o4;
      o4.x = f2bf(oa[dt][4 * g + 0] * inv);
      o4.y = f2bf(oa[dt][4 * g + 1] * inv);
      o4.z = f2bf(oa[dt][4 * g + 2] * inv);
      o4.w = f2bf(oa[dt][4 * g + 3] * inv);
      *(ushort4*)&O[qgrow * 1024 + h * 64 + dt * 32 + 8 * g + 4 * hi] = o4;
    }
}

// ---------------- launch ----------------
extern "C" void kernel_launch(void* const* d_in, const int* in_sizes, int n_in,
                              void* d_out, int out_size, void* d_ws, size_t ws_size,
                              hipStream_t stream) {
  const float* x  = (const float*)d_in[0];
  const float* Wq = (const float*)d_in[1];
  const float* Wk = (const float*)d_in[2];
  const float* Wv = (const float*)d_in[3];
  const float* Wo = (const float*)d_in[4];
  char* ws = (char*)d_ws;
  unsigned short* xb   = (unsigned short*)(ws);                    // 8 MiB (x bf16; later Vt)
  unsigned short* Wb   = (unsigned short*)(ws + (8u << 20));       // 6 MiB
  unsigned short* Wob  = (unsigned short*)(ws + (14u << 20));      // 2 MiB
  unsigned short* QKVb = (unsigned short*)(ws + (16u << 20));      // 24 MiB
  unsigned short* Ob   = (unsigned short*)(ws + (40u << 20));      // 8 MiB
  unsigned short* Vtg  = xb;                                       // reuse: x dead after QKV GEMM

  cvt_all<<<8192, 256, 0, stream>>>(x, Wq, Wk, Wv, Wo, xb, Wb, Wob);
  gemm_bt<0><<<dim3(32, 24), 256, 0, stream>>>(xb, Wb, QKVb, 3072, 1024);
  ropevtr_k<<<5120, 256, 0, stream>>>(QKVb, Vtg);
  attn_k<<<dim3(32, 16), 256, 0, stream>>>(QKVb, Vtg, Ob);
  gemm2_bt<<<dim3(64, 8), 128, 0, stream>>>(Ob, Wob, (float*)d_out, 1024, 1024);
}

// Round 25
// 121.506 us; speedup vs baseline: 1.0048x; 1.0048x over previous
//
#include <hip/hip_runtime.h>

typedef __attribute__((ext_vector_type(8))) short bf16x8;
typedef __attribute__((ext_vector_type(4))) float f32x4;
typedef __attribute__((ext_vector_type(16))) float f32x16;

typedef const __attribute__((address_space(1))) unsigned int gu32;
typedef __attribute__((address_space(3))) unsigned int lu32;

__device__ __forceinline__ void async16(const void* g, void* l) {
  __builtin_amdgcn_global_load_lds((gu32*)g, (lu32*)l, 16, 0, 0);
}

__device__ __forceinline__ unsigned short f2bf(float f) {
  unsigned int u = __float_as_uint(f);
  u += 0x7fffu + ((u >> 16) & 1u);
  return (unsigned short)(u >> 16);
}
__device__ __forceinline__ float b2f(unsigned short s) {
  return __uint_as_float(((unsigned int)s) << 16);
}
__device__ __forceinline__ unsigned int cvtpk(float lo, float hi) {
  unsigned int w;
  asm("v_cvt_pk_bf16_f32 %0, %1, %2" : "=v"(w) : "v"(lo), "v"(hi));
  return w;
}
__device__ __forceinline__ void plswap(unsigned int& x, unsigned int& y) {
  asm("v_permlane32_swap_b32 %0, %1" : "+v"(x), "+v"(y));
}
__device__ __forceinline__ float max3f(float a, float b, float c) {
  float d;
  asm("v_max3_f32 %0, %1, %2, %3" : "=v"(d) : "v"(a), "v"(b), "v"(c));
  return d;
}

// ---------------- all fp32 -> bf16 conversions in one launch ----------------
__global__ __launch_bounds__(256) void cvt_all(const float* __restrict__ x,
                                               const float* __restrict__ Wq,
                                               const float* __restrict__ Wk,
                                               const float* __restrict__ Wv,
                                               const float* __restrict__ Wo,
                                               unsigned short* __restrict__ xb,
                                               unsigned short* __restrict__ Wb,
                                               unsigned short* __restrict__ Wob) {
  int i = blockIdx.x * 256 + threadIdx.x;
  const float* src;
  unsigned short* dst;
  int j;
  if (i < (1 << 20)) {
    src = x; dst = xb; j = i;
  } else {
    int k = i - (1 << 20);
    int wsel = k >> 18;
    j = k & 0x3FFFF;
    src = (wsel == 0) ? Wq : (wsel == 1) ? Wk : (wsel == 2) ? Wv : Wo;
    dst = (wsel == 0) ? Wb : (wsel == 1) ? Wb + (1 << 20)
        : (wsel == 2) ? Wb + (2 << 20) : Wob;
  }
  float4 v = ((const float4*)src)[j];
  ushort4 o;
  o.x = f2bf(v.x); o.y = f2bf(v.y); o.z = f2bf(v.z); o.w = f2bf(v.w);
  ((ushort4*)dst)[j] = o;
}

// ---------------- QKV GEMM (R15, unchanged) ----------------
template <int WRITE_F32>
__global__ __launch_bounds__(256) void gemm_bt(const unsigned short* __restrict__ A,
                                               const unsigned short* __restrict__ B,
                                               void* __restrict__ Cp, int N, int K) {
  __shared__ __align__(16) unsigned short Al[3][128 * 32];
  __shared__ __align__(16) unsigned short Bl[3][128 * 32];
  const int t = threadIdx.x;
  const int w = t >> 6, l = t & 63;
  const int wm = w >> 1, wn = w & 1;
  const int lr = l & 15, lg = l >> 4;
  const long bm = (long)blockIdx.x * 128, bn = (long)blockIdx.y * 128;
  const int srow = t >> 2;
  const int c8 = t & 3;
  const int KT = K >> 5;
  f32x4 acc[4][4] = {};

  auto STAGE = [&](int ts) {
    const int bi = ts % 3;
    const int k0 = ts * 32;
    #pragma unroll
    for (int r = 0; r < 2; ++r) {
      int row = r * 64 + srow;
      async16(&A[(bm + row) * (long)K + k0 + c8 * 8], &Al[bi][row * 32 + c8 * 8]);
      async16(&B[(bn + row) * (long)K + k0 + c8 * 8], &Bl[bi][row * 32 + c8 * 8]);
    }
  };

  STAGE(0);
  STAGE(1);
  for (int kt = 0; kt < KT; ++kt) {
    const int cur = kt % 3;
    if (kt < KT - 1) asm volatile("s_waitcnt vmcnt(4)" ::: "memory");
    else             asm volatile("s_waitcnt vmcnt(0)" ::: "memory");
    __builtin_amdgcn_s_barrier();
    __builtin_amdgcn_sched_barrier(0);
    if (kt + 2 < KT) STAGE(kt + 2);
    bf16x8 af[4], bf[4];
    #pragma unroll
    for (int i = 0; i < 4; ++i) {
      af[i] = *(const bf16x8*)&Al[cur][(wm * 64 + i * 16 + lr) * 32 + lg * 8];
      bf[i] = *(const bf16x8*)&Bl[cur][(wn * 64 + i * 16 + lr) * 32 + lg * 8];
    }
    #pragma unroll
    for (int i = 0; i < 4; ++i)
      #pragma unroll
      for (int j = 0; j < 4; ++j)
        acc[i][j] = __builtin_amdgcn_mfma_f32_16x16x32_bf16(af[i], bf[j], acc[i][j], 0, 0, 0);
  }
  #pragma unroll
  for (int i = 0; i < 4; ++i)
    #pragma unroll
    for (int j = 0; j < 4; ++j)
      #pragma unroll
      for (int r = 0; r < 4; ++r) {
        long row = bm + wm * 64 + i * 16 + lg * 4 + r;
        long col = bn + wn * 64 + j * 16 + lr;
        float v = acc[i][j][r];
        if (WRITE_F32) ((float*)Cp)[row * N + col] = v;
        else ((unsigned short*)Cp)[row * N + col] = f2bf(v);
      }
}

// ---------------- proj GEMM (R16, unchanged) ----------------
__global__ __launch_bounds__(128) void gemm2_bt(const unsigned short* __restrict__ A,
                                                const unsigned short* __restrict__ B,
                                                float* __restrict__ Cp, int N, int K) {
  __shared__ __align__(16) unsigned short Al[3][64 * 32];
  __shared__ __align__(16) unsigned short Bl[3][128 * 32];
  const int t = threadIdx.x;
  const int w = t >> 6, l = t & 63;
  const int lr = l & 15, lg = l >> 4;
  const long bm = (long)blockIdx.x * 64, bn = (long)blockIdx.y * 128;
  const int KT = K >> 5;
  f32x4 acc[4][4] = {};

  auto STAGE = [&](int ts) {
    const int bi = ts % 3;
    const int k0 = ts * 32;
    #pragma unroll
    for (int r = 0; r < 2; ++r) {
      int u = r * 128 + 64 * w + l;
      int row = u >> 2, c8 = u & 3;
      async16(&A[(bm + row) * (long)K + k0 + c8 * 8], &Al[bi][row * 32 + c8 * 8]);
    }
    #pragma unroll
    for (int r = 0; r < 4; ++r) {
      int u = r * 128 + 64 * w + l;
      int row = u >> 2, c8 = u & 3;
      async16(&B[(bn + row) * (long)K + k0 + c8 * 8], &Bl[bi][row * 32 + c8 * 8]);
    }
  };

  STAGE(0);
  STAGE(1);
  for (int kt = 0; kt < KT; ++kt) {
    const int cur = kt % 3;
    if (kt < KT - 1) asm volatile("s_waitcnt vmcnt(6)" ::: "memory");
    else             asm volatile("s_waitcnt vmcnt(0)" ::: "memory");
    __builtin_amdgcn_s_barrier();
    __builtin_amdgcn_sched_barrier(0);
    if (kt + 2 < KT) STAGE(kt + 2);
    bf16x8 af[4], bf[4];
    #pragma unroll
    for (int i = 0; i < 4; ++i) {
      af[i] = *(const bf16x8*)&Al[cur][(i * 16 + lr) * 32 + lg * 8];
      bf[i] = *(const bf16x8*)&Bl[cur][(w * 64 + i * 16 + lr) * 32 + lg * 8];
    }
    #pragma unroll
    for (int i = 0; i < 4; ++i)
      #pragma unroll
      for (int j = 0; j < 4; ++j)
        acc[i][j] = __builtin_amdgcn_mfma_f32_16x16x32_bf16(af[i], bf[j], acc[i][j], 0, 0, 0);
  }
  #pragma unroll
  for (int i = 0; i < 4; ++i)
    #pragma unroll
    for (int j = 0; j < 4; ++j)
      #pragma unroll
      for (int r = 0; r < 4; ++r) {
        long row = bm + i * 16 + lg * 4 + r;
        long col = bn + w * 64 + j * 16 + lr;
        Cp[row * N + col] = acc[i][j][r];
      }
}

// ---------------- fused RoPE (Q,K) + V-transpose (R16, unchanged) ----------
__global__ __launch_bounds__(256) void ropevtr_k(unsigned short* __restrict__ QKV,
                                                 unsigned short* __restrict__ Vt) {
  __shared__ unsigned short tl[64][66];
  const int bx = blockIdx.x;
  const int t = threadIdx.x;
  if (bx < 4096) {
    float* csl = (float*)&tl[0][0];
    float* snl = csl + 32;
    const int row = bx;
    const int s = row & 2047;
    if (t < 32) {
      float invf = exp2f((float)t * (-13.287712379549449f / 32.0f));
      float sn, cs;
      sincosf((float)s * invf, &sn, &cs);
      csl[t] = cs; snl[t] = sn;
    }
    __syncthreads();
    const int col0 = (t < 128) ? t * 8 : 1024 + (t - 128) * 8;
    const int i0 = (t & 7) * 4;
    unsigned short* p = &QKV[(size_t)row * 3072 + col0];
    bf16x8 v = *(const bf16x8*)p;
    bf16x8 o;
    #pragma unroll
    for (int j = 0; j < 4; ++j) {
      float x1 = b2f((unsigned short)v[2 * j]);
      float x2 = b2f((unsigned short)v[2 * j + 1]);
      float cs = csl[i0 + j], sn = snl[i0 + j];
      o[2 * j]     = (short)f2bf(x1 * cs - x2 * sn);
      o[2 * j + 1] = (short)f2bf(x1 * sn + x2 * cs);
    }
    *(bf16x8*)p = o;
  } else {
    const int idx = bx - 4096;
    const int kt = idx & 31;
    const int bh = idx >> 5;
    const int b = bh >> 4, h = bh & 15;
    const int row = t >> 3, c8 = t & 7;
    #pragma unroll
    for (int r = 0; r < 2; ++r) {
      int k = r * 32 + row;
      bf16x8 v = *(const bf16x8*)&QKV[((long)b * 2048 + kt * 64 + k) * 3072 + 2048 + h * 64 + c8 * 8];
      #pragma unroll
      for (int j = 0; j < 8; ++j) tl[c8 * 8 + j][k] = (unsigned short)v[j];
    }
    __syncthreads();
    #pragma unroll
    for (int r = 0; r < 2; ++r) {
      int d = r * 32 + row;
      ushort4 a, bq;
      a.x = tl[d][c8 * 8 + 0]; a.y = tl[d][c8 * 8 + 1];
      a.z = tl[d][c8 * 8 + 2]; a.w = tl[d][c8 * 8 + 3];
      bq.x = tl[d][c8 * 8 + 4]; bq.y = tl[d][c8 * 8 + 5];
      bq.z = tl[d][c8 * 8 + 6]; bq.w = tl[d][c8 * 8 + 7];
      long off = ((long)bh * 64 + d) * 2048 + kt * 64 + c8 * 8;
      *(ushort4*)&Vt[off] = a;
      *(ushort4*)&Vt[off + 4] = bq;
    }
  }
}

// ---------------- causal flash attention: 128 KV rows per step (R17) -------
// One barrier + vmcnt drain + mask/max/rescale sequence per TWO 64-row KV
// tiles. QK = 4 independent 4-deep MFMA chains; 64 exps batched. Mask rule:
// tile kt >= ktmax -> apply triangle (kt > ktmax wipes the tile entirely),
// so all waves run all steps uniformly. V stays LDS-staged (R22's V-direct
// regressed 47->72 us: load latency landed on the PV MFMA chain).
__global__ __launch_bounds__(256) void attn_k(const unsigned short* __restrict__ QKV,
                                              const unsigned short* __restrict__ VtG,
                                              unsigned short* __restrict__ O) {
  __shared__ __align__(16) unsigned short Kl[2][2][64 * 64];
  __shared__ __align__(16) unsigned short Vl[2][2][64 * 64];
  const int t = threadIdx.x;
  const int w = t >> 6, l = t & 63;
  const int q31 = l & 31, hi = l >> 5;
  const int bh = blockIdx.x;               // same head -> same XCD
  const int y = (int)blockIdx.y;
  const int qt = (y < 8) ? (15 - y) : (y - 8);
  const int b = bh >> 4, h = bh & 15;
  const int Qb = qt * 128;
  const long rowb = (long)b * 2048;
  const int L = 3072;
  const int NTS = qt + 1;                  // steps of 128 KV rows
  const float cexp = 0.125f * 1.4426950408889634f;

  const int qmy = Qb + 32 * w + q31;
  const long qgrow = rowb + qmy;
  const int ktmax = (Qb + 32 * w) >> 6;    // wave-uniform diagonal tile

  bf16x8 qf[4];
  #pragma unroll
  for (int dk = 0; dk < 4; ++dk)
    qf[dk] = *(const bf16x8*)&QKV[qgrow * L + h * 64 + dk * 16 + hi * 8];

  bf16x8 onesf;
  #pragma unroll
  for (int j = 0; j < 8; ++j) onesf[j] = (short)0x3F80;

  float m_ = -1e30f;
  f32x16 oa[2], la;
  #pragma unroll
  for (int r = 0; r < 16; ++r) { oa[0][r] = 0.0f; oa[1][r] = 0.0f; la[r] = 0.0f; }

  auto STAGE2 = [&](int ts) {   // 8 async16/thread: 2 tiles x (2 K + 2 V)
    const int bi = ts & 1;
    const long vrowb = (long)bh * 64;
    #pragma unroll
    for (int s = 0; s < 2; ++s) {
      const int kt = 2 * ts + s;
      const long kb = rowb + (long)kt * 64;
      #pragma unroll
      for (int r = 0; r < 2; ++r) {
        int row = w * 16 + r * 8 + (l >> 3);
        int c8s = ((l & 7) ^ (row & 7)) * 8;
        async16(&QKV[(kb + row) * L + 1024 + h * 64 + c8s], &Kl[bi][s][row * 64 + (l & 7) * 8]);
        async16(&VtG[(vrowb + row) * 2048 + kt * 64 + c8s], &Vl[bi][s][row * 64 + (l & 7) * 8]);
      }
    }
  };

  STAGE2(0);

  for (int ts = 0; ts < NTS; ++ts) {
    const int bi = ts & 1;
    asm volatile("s_waitcnt vmcnt(0)" ::: "memory");   // STAGE2(ts) landed
    __builtin_amdgcn_s_barrier();                      // prev step's readers done
    __builtin_amdgcn_sched_barrier(0);
    if (ts + 1 < NTS) STAGE2(ts + 1);

    // ---- S^T for both tiles: 4 independent 4-deep MFMA chains ----
    f32x16 st[2][2];
    #pragma unroll
    for (int s = 0; s < 2; ++s)
      #pragma unroll
      for (int kt2 = 0; kt2 < 2; ++kt2)
        #pragma unroll
        for (int r = 0; r < 16; ++r) st[s][kt2][r] = 0.0f;
    __builtin_amdgcn_s_setprio(1);
    #pragma unroll
    for (int dk = 0; dk < 4; ++dk)
      #pragma unroll
      for (int s = 0; s < 2; ++s)
        #pragma unroll
        for (int kt2 = 0; kt2 < 2; ++kt2) {
          int krow = kt2 * 32 + q31;
          bf16x8 kfr = *(const bf16x8*)&Kl[bi][s][krow * 64 + (((2 * dk + hi) ^ (krow & 7)) * 8)];
          st[s][kt2] = __builtin_amdgcn_mfma_f32_32x32x16_bf16(kfr, qf[dk], st[s][kt2], 0, 0, 0);
        }
    __builtin_amdgcn_s_setprio(0);
    // ---- causal mask: tile kt >= ktmax (kt > ktmax wipes fully) ----
    #pragma unroll
    for (int s = 0; s < 2; ++s) {
      int kt = 2 * ts + s;
      if (kt >= ktmax) {
        #pragma unroll
        for (int kt2 = 0; kt2 < 2; ++kt2)
          #pragma unroll
          for (int r = 0; r < 16; ++r) {
            int kg = kt * 64 + kt2 * 32 + (r & 3) + 8 * (r >> 2) + 4 * hi;
            if (kg > qmy) st[s][kt2][r] = -1e30f;
          }
      }
    }
    // ---- online softmax over 128 cols, one sequence per step ----
    float m0[8];
    #pragma unroll
    for (int i = 0; i < 8; ++i)
      m0[i] = fmaxf(fmaxf(max3f(st[0][0][i], st[0][0][i + 8], st[0][1][i]),
                          max3f(st[0][1][i + 8], st[1][0][i], st[1][0][i + 8])),
                    fmaxf(st[1][1][i], st[1][1][i + 8]));
    float mt = max3f(max3f(m0[0], m0[1], m0[2]), max3f(m0[3], m0[4], m0[5]),
                     fmaxf(m0[6], m0[7]));
    if (__any((mt - m_) * cexp > 8.0f)) {   // defer-max (T13)
      float mg = fmaxf(mt, __shfl_xor(mt, 32, 64));
      float mn = fmaxf(m_, mg);
      float al = __builtin_amdgcn_exp2f((m_ - mn) * cexp);
      m_ = mn;
      la[0] *= al;
      #pragma unroll
      for (int dt = 0; dt < 2; ++dt)
        #pragma unroll
        for (int r = 0; r < 16; ++r) oa[dt][r] *= al;
    }
    const float mc = m_ * cexp;
    #pragma unroll
    for (int s = 0; s < 2; ++s)
      #pragma unroll
      for (int kt2 = 0; kt2 < 2; ++kt2)
        #pragma unroll
        for (int r = 0; r < 16; ++r)
          st[s][kt2][r] = __builtin_amdgcn_exp2f(fmaf(st[s][kt2][r], cexp, -mc));
    // ---- per tile: pack P, then PV + l on the matrix pipe ----
    #pragma unroll
    for (int s = 0; s < 2; ++s) {
      bf16x8 pfr[4];
      #pragma unroll
      for (int ks = 0; ks < 4; ++ks) {
        int tt = ks >> 1, gX = 2 * (ks & 1), gY = gX + 1;
        unsigned int x1 = cvtpk(st[s][tt][4 * gX + 0], st[s][tt][4 * gX + 1]);
        unsigned int y1 = cvtpk(st[s][tt][4 * gY + 0], st[s][tt][4 * gY + 1]);
        plswap(x1, y1);
        unsigned int x2 = cvtpk(st[s][tt][4 * gX + 2], st[s][tt][4 * gX + 3]);
        unsigned int y2 = cvtpk(st[s][tt][4 * gY + 2], st[s][tt][4 * gY + 3]);
        plswap(x2, y2);
        union { unsigned int u[4]; bf16x8 b; } cc;
        cc.u[0] = x1; cc.u[1] = x2; cc.u[2] = y1; cc.u[3] = y2;
        pfr[ks] = cc.b;
      }
      __builtin_amdgcn_s_setprio(1);
      #pragma unroll
      for (int ks = 0; ks < 4; ++ks) {
        la = __builtin_amdgcn_mfma_f32_32x32x16_bf16(onesf, pfr[ks], la, 0, 0, 0);
        #pragma unroll
        for (int dt = 0; dt < 2; ++dt) {
          int vrow = dt * 32 + q31;
          bf16x8 vf = *(const bf16x8*)&Vl[bi][s][vrow * 64 + (((2 * ks + hi) ^ (vrow & 7)) * 8)];
          oa[dt] = __builtin_amdgcn_mfma_f32_32x32x16_bf16(vf, pfr[ks], oa[dt], 0, 0, 0);
        }
      }
      __builtin_amdgcn_s_setprio(0);
    }
  }

  float inv = 1.0f / la[0];
  #pragma unroll
  for (int dt = 0; dt < 2; ++dt)
    #pragma unroll
    for (int g = 0; g < 4; ++g) {
      ushort4 o4;
      o4.x = f2bf(oa[dt][4 * g + 0] * inv);
      o4.y = f2bf(oa[dt][4 * g + 1] * inv);
      o4.z = f2bf(oa[dt][4 * g + 2] * inv);
      o4.w = f2bf(oa[dt][4 * g + 3] * inv);
      *(ushort4*)&O[qgrow * 1024 + h * 64 + dt * 32 + 8 * g + 4 * hi] = o4;
    }
}

// ---------------- launch ----------------
extern "C" void kernel_launch(void* const* d_in, const int* in_sizes, int n_in,
                              void* d_out, int out_size, void* d_ws, size_t ws_size,
                              hipStream_t stream) {
  const float* x  = (const float*)d_in[0];
  const float* Wq = (const float*)d_in[1];
  const float* Wk = (const float*)d_in[2];
  const float* Wv = (const float*)d_in[3];
  const float* Wo = (const float*)d_in[4];
  char* ws = (char*)d_ws;
  unsigned short* xb   = (unsigned short*)(ws);                    // 8 MiB (x bf16; later Vt)
  unsigned short* Wb   = (unsigned short*)(ws + (8u << 20));       // 6 MiB
  unsigned short* Wob  = (unsigned short*)(ws + (14u << 20));      // 2 MiB
  unsigned short* QKVb = (unsigned short*)(ws + (16u << 20));      // 24 MiB
  unsigned short* Ob   = (unsigned short*)(ws + (40u << 20));      // 8 MiB
  unsigned short* Vtg  = xb;                                       // reuse: x dead after QKV GEMM

  cvt_all<<<8192, 256, 0, stream>>>(x, Wq, Wk, Wv, Wo, xb, Wb, Wob);
  gemm_bt<0><<<dim3(32, 24), 256, 0, stream>>>(xb, Wb, QKVb, 3072, 1024);
  ropevtr_k<<<5120, 256, 0, stream>>>(QKVb, Vtg);
  attn_k<<<dim3(32, 16), 256, 0, stream>>>(QKVb, Vtg, Ob);
  gemm2_bt<<<dim3(64, 8), 128, 0, stream>>>(Ob, Wob, (float*)d_out, 1024, 1024);
}

// Round 26
// 121.241 us; speedup vs baseline: 1.0070x; 1.0022x over previous
//
#include <hip/hip_runtime.h>

typedef __attribute__((ext_vector_type(8))) short bf16x8;
typedef __attribute__((ext_vector_type(4))) float f32x4;
typedef __attribute__((ext_vector_type(16))) float f32x16;

typedef const __attribute__((address_space(1))) unsigned int gu32;
typedef __attribute__((address_space(3))) unsigned int lu32;

__device__ __forceinline__ void async16(const void* g, void* l) {
  __builtin_amdgcn_global_load_lds((gu32*)g, (lu32*)l, 16, 0, 0);
}

__device__ __forceinline__ unsigned short f2bf(float f) {
  unsigned int u = __float_as_uint(f);
  u += 0x7fffu + ((u >> 16) & 1u);
  return (unsigned short)(u >> 16);
}
__device__ __forceinline__ float b2f(unsigned short s) {
  return __uint_as_float(((unsigned int)s) << 16);
}
__device__ __forceinline__ unsigned int cvtpk(float lo, float hi) {
  unsigned int w;
  asm("v_cvt_pk_bf16_f32 %0, %1, %2" : "=v"(w) : "v"(lo), "v"(hi));
  return w;
}
__device__ __forceinline__ void plswap(unsigned int& x, unsigned int& y) {
  asm("v_permlane32_swap_b32 %0, %1" : "+v"(x), "+v"(y));
}
__device__ __forceinline__ float max3f(float a, float b, float c) {
  float d;
  asm("v_max3_f32 %0, %1, %2, %3" : "=v"(d) : "v"(a), "v"(b), "v"(c));
  return d;
}

// ---------------- all fp32 -> bf16 conversions in one launch ----------------
__global__ __launch_bounds__(256) void cvt_all(const float* __restrict__ x,
                                               const float* __restrict__ Wq,
                                               const float* __restrict__ Wk,
                                               const float* __restrict__ Wv,
                                               const float* __restrict__ Wo,
                                               unsigned short* __restrict__ xb,
                                               unsigned short* __restrict__ Wb,
                                               unsigned short* __restrict__ Wob) {
  int i = blockIdx.x * 256 + threadIdx.x;
  const float* src;
  unsigned short* dst;
  int j;
  if (i < (1 << 20)) {
    src = x; dst = xb; j = i;
  } else {
    int k = i - (1 << 20);
    int wsel = k >> 18;
    j = k & 0x3FFFF;
    src = (wsel == 0) ? Wq : (wsel == 1) ? Wk : (wsel == 2) ? Wv : Wo;
    dst = (wsel == 0) ? Wb : (wsel == 1) ? Wb + (1 << 20)
        : (wsel == 2) ? Wb + (2 << 20) : Wob;
  }
  float4 v = ((const float4*)src)[j];
  ushort4 o;
  o.x = f2bf(v.x); o.y = f2bf(v.y); o.z = f2bf(v.z); o.w = f2bf(v.w);
  ((ushort4*)dst)[j] = o;
}

// ---------------- QKV GEMM (R15, unchanged) ----------------
template <int WRITE_F32>
__global__ __launch_bounds__(256) void gemm_bt(const unsigned short* __restrict__ A,
                                               const unsigned short* __restrict__ B,
                                               void* __restrict__ Cp, int N, int K) {
  __shared__ __align__(16) unsigned short Al[3][128 * 32];
  __shared__ __align__(16) unsigned short Bl[3][128 * 32];
  const int t = threadIdx.x;
  const int w = t >> 6, l = t & 63;
  const int wm = w >> 1, wn = w & 1;
  const int lr = l & 15, lg = l >> 4;
  const long bm = (long)blockIdx.x * 128, bn = (long)blockIdx.y * 128;
  const int srow = t >> 2;
  const int c8 = t & 3;
  const int KT = K >> 5;
  f32x4 acc[4][4] = {};

  auto STAGE = [&](int ts) {
    const int bi = ts % 3;
    const int k0 = ts * 32;
    #pragma unroll
    for (int r = 0; r < 2; ++r) {
      int row = r * 64 + srow;
      async16(&A[(bm + row) * (long)K + k0 + c8 * 8], &Al[bi][row * 32 + c8 * 8]);
      async16(&B[(bn + row) * (long)K + k0 + c8 * 8], &Bl[bi][row * 32 + c8 * 8]);
    }
  };

  STAGE(0);
  STAGE(1);
  for (int kt = 0; kt < KT; ++kt) {
    const int cur = kt % 3;
    if (kt < KT - 1) asm volatile("s_waitcnt vmcnt(4)" ::: "memory");
    else             asm volatile("s_waitcnt vmcnt(0)" ::: "memory");
    __builtin_amdgcn_s_barrier();
    __builtin_amdgcn_sched_barrier(0);
    if (kt + 2 < KT) STAGE(kt + 2);
    bf16x8 af[4], bf[4];
    #pragma unroll
    for (int i = 0; i < 4; ++i) {
      af[i] = *(const bf16x8*)&Al[cur][(wm * 64 + i * 16 + lr) * 32 + lg * 8];
      bf[i] = *(const bf16x8*)&Bl[cur][(wn * 64 + i * 16 + lr) * 32 + lg * 8];
    }
    #pragma unroll
    for (int i = 0; i < 4; ++i)
      #pragma unroll
      for (int j = 0; j < 4; ++j)
        acc[i][j] = __builtin_amdgcn_mfma_f32_16x16x32_bf16(af[i], bf[j], acc[i][j], 0, 0, 0);
  }
  #pragma unroll
  for (int i = 0; i < 4; ++i)
    #pragma unroll
    for (int j = 0; j < 4; ++j)
      #pragma unroll
      for (int r = 0; r < 4; ++r) {
        long row = bm + wm * 64 + i * 16 + lg * 4 + r;
        long col = bn + wn * 64 + j * 16 + lr;
        float v = acc[i][j][r];
        if (WRITE_F32) ((float*)Cp)[row * N + col] = v;
        else ((unsigned short*)Cp)[row * N + col] = f2bf(v);
      }
}

// ---------------- proj GEMM (R16, unchanged) ----------------
__global__ __launch_bounds__(128) void gemm2_bt(const unsigned short* __restrict__ A,
                                                const unsigned short* __restrict__ B,
                                                float* __restrict__ Cp, int N, int K) {
  __shared__ __align__(16) unsigned short Al[3][64 * 32];
  __shared__ __align__(16) unsigned short Bl[3][128 * 32];
  const int t = threadIdx.x;
  const int w = t >> 6, l = t & 63;
  const int lr = l & 15, lg = l >> 4;
  const long bm = (long)blockIdx.x * 64, bn = (long)blockIdx.y * 128;
  const int KT = K >> 5;
  f32x4 acc[4][4] = {};

  auto STAGE = [&](int ts) {
    const int bi = ts % 3;
    const int k0 = ts * 32;
    #pragma unroll
    for (int r = 0; r < 2; ++r) {
      int u = r * 128 + 64 * w + l;
      int row = u >> 2, c8 = u & 3;
      async16(&A[(bm + row) * (long)K + k0 + c8 * 8], &Al[bi][row * 32 + c8 * 8]);
    }
    #pragma unroll
    for (int r = 0; r < 4; ++r) {
      int u = r * 128 + 64 * w + l;
      int row = u >> 2, c8 = u & 3;
      async16(&B[(bn + row) * (long)K + k0 + c8 * 8], &Bl[bi][row * 32 + c8 * 8]);
    }
  };

  STAGE(0);
  STAGE(1);
  for (int kt = 0; kt < KT; ++kt) {
    const int cur = kt % 3;
    if (kt < KT - 1) asm volatile("s_waitcnt vmcnt(6)" ::: "memory");
    else             asm volatile("s_waitcnt vmcnt(0)" ::: "memory");
    __builtin_amdgcn_s_barrier();
    __builtin_amdgcn_sched_barrier(0);
    if (kt + 2 < KT) STAGE(kt + 2);
    bf16x8 af[4], bf[4];
    #pragma unroll
    for (int i = 0; i < 4; ++i) {
      af[i] = *(const bf16x8*)&Al[cur][(i * 16 + lr) * 32 + lg * 8];
      bf[i] = *(const bf16x8*)&Bl[cur][(w * 64 + i * 16 + lr) * 32 + lg * 8];
    }
    #pragma unroll
    for (int i = 0; i < 4; ++i)
      #pragma unroll
      for (int j = 0; j < 4; ++j)
        acc[i][j] = __builtin_amdgcn_mfma_f32_16x16x32_bf16(af[i], bf[j], acc[i][j], 0, 0, 0);
  }
  #pragma unroll
  for (int i = 0; i < 4; ++i)
    #pragma unroll
    for (int j = 0; j < 4; ++j)
      #pragma unroll
      for (int r = 0; r < 4; ++r) {
        long row = bm + i * 16 + lg * 4 + r;
        long col = bn + w * 64 + j * 16 + lr;
        Cp[row * N + col] = acc[i][j][r];
      }
}

// ---------------- fused RoPE (Q,K) + V-transpose (R16, unchanged) ----------
__global__ __launch_bounds__(256) void ropevtr_k(unsigned short* __restrict__ QKV,
                                                 unsigned short* __restrict__ Vt) {
  __shared__ unsigned short tl[64][66];
  const int bx = blockIdx.x;
  const int t = threadIdx.x;
  if (bx < 4096) {
    float* csl = (float*)&tl[0][0];
    float* snl = csl + 32;
    const int row = bx;
    const int s = row & 2047;
    if (t < 32) {
      float invf = exp2f((float)t * (-13.287712379549449f / 32.0f));
      float sn, cs;
      sincosf((float)s * invf, &sn, &cs);
      csl[t] = cs; snl[t] = sn;
    }
    __syncthreads();
    const int col0 = (t < 128) ? t * 8 : 1024 + (t - 128) * 8;
    const int i0 = (t & 7) * 4;
    unsigned short* p = &QKV[(size_t)row * 3072 + col0];
    bf16x8 v = *(const bf16x8*)p;
    bf16x8 o;
    #pragma unroll
    for (int j = 0; j < 4; ++j) {
      float x1 = b2f((unsigned short)v[2 * j]);
      float x2 = b2f((unsigned short)v[2 * j + 1]);
      float cs = csl[i0 + j], sn = snl[i0 + j];
      o[2 * j]     = (short)f2bf(x1 * cs - x2 * sn);
      o[2 * j + 1] = (short)f2bf(x1 * sn + x2 * cs);
    }
    *(bf16x8*)p = o;
  } else {
    const int idx = bx - 4096;
    const int kt = idx & 31;
    const int bh = idx >> 5;
    const int b = bh >> 4, h = bh & 15;
    const int row = t >> 3, c8 = t & 7;
    #pragma unroll
    for (int r = 0; r < 2; ++r) {
      int k = r * 32 + row;
      bf16x8 v = *(const bf16x8*)&QKV[((long)b * 2048 + kt * 64 + k) * 3072 + 2048 + h * 64 + c8 * 8];
      #pragma unroll
      for (int j = 0; j < 8; ++j) tl[c8 * 8 + j][k] = (unsigned short)v[j];
    }
    __syncthreads();
    #pragma unroll
    for (int r = 0; r < 2; ++r) {
      int d = r * 32 + row;
      ushort4 a, bq;
      a.x = tl[d][c8 * 8 + 0]; a.y = tl[d][c8 * 8 + 1];
      a.z = tl[d][c8 * 8 + 2]; a.w = tl[d][c8 * 8 + 3];
      bq.x = tl[d][c8 * 8 + 4]; bq.y = tl[d][c8 * 8 + 5];
      bq.z = tl[d][c8 * 8 + 6]; bq.w = tl[d][c8 * 8 + 7];
      long off = ((long)bh * 64 + d) * 2048 + kt * 64 + c8 * 8;
      *(ushort4*)&Vt[off] = a;
      *(ushort4*)&Vt[off + 4] = bq;
    }
  }
}

// ---------------- causal flash attention: 128 KV rows per step (R17) -------
// One barrier + vmcnt drain + mask/max/rescale sequence per TWO 64-row KV
// tiles. QK = 4 independent 4-deep MFMA chains; 64 exps batched. Mask rule:
// tile kt >= ktmax -> apply triangle (kt > ktmax wipes the tile entirely),
// so all waves run all steps uniformly. V stays LDS-staged (R22's V-direct
// regressed 47->72 us: load latency landed on the PV MFMA chain).
__global__ __launch_bounds__(256) void attn_k(const unsigned short* __restrict__ QKV,
                                              const unsigned short* __restrict__ VtG,
                                              unsigned short* __restrict__ O) {
  __shared__ __align__(16) unsigned short Kl[2][2][64 * 64];
  __shared__ __align__(16) unsigned short Vl[2][2][64 * 64];
  const int t = threadIdx.x;
  const int w = t >> 6, l = t & 63;
  const int q31 = l & 31, hi = l >> 5;
  const int bh = blockIdx.x;               // same head -> same XCD
  const int y = (int)blockIdx.y;
  const int qt = (y < 8) ? (15 - y) : (y - 8);
  const int b = bh >> 4, h = bh & 15;
  const int Qb = qt * 128;
  const long rowb = (long)b * 2048;
  const int L = 3072;
  const int NTS = qt + 1;                  // steps of 128 KV rows
  const float cexp = 0.125f * 1.4426950408889634f;

  const int qmy = Qb + 32 * w + q31;
  const long qgrow = rowb + qmy;
  const int ktmax = (Qb + 32 * w) >> 6;    // wave-uniform diagonal tile

  bf16x8 qf[4];
  #pragma unroll
  for (int dk = 0; dk < 4; ++dk)
    qf[dk] = *(const bf16x8*)&QKV[qgrow * L + h * 64 + dk * 16 + hi * 8];

  bf16x8 onesf;
  #pragma unroll
  for (int j = 0; j < 8; ++j) onesf[j] = (short)0x3F80;

  float m_ = -1e30f;
  f32x16 oa[2], la;
  #pragma unroll
  for (int r = 0; r < 16; ++r) { oa[0][r] = 0.0f; oa[1][r] = 0.0f; la[r] = 0.0f; }

  auto STAGE2 = [&](int ts) {   // 8 async16/thread: 2 tiles x (2 K + 2 V)
    const int bi = ts & 1;
    const long vrowb = (long)bh * 64;
    #pragma unroll
    for (int s = 0; s < 2; ++s) {
      const int kt = 2 * ts + s;
      const long kb = rowb + (long)kt * 64;
      #pragma unroll
      for (int r = 0; r < 2; ++r) {
        int row = w * 16 + r * 8 + (l >> 3);
        int c8s = ((l & 7) ^ (row & 7)) * 8;
        async16(&QKV[(kb + row) * L + 1024 + h * 64 + c8s], &Kl[bi][s][row * 64 + (l & 7) * 8]);
        async16(&VtG[(vrowb + row) * 2048 + kt * 64 + c8s], &Vl[bi][s][row * 64 + (l & 7) * 8]);
      }
    }
  };

  STAGE2(0);

  for (int ts = 0; ts < NTS; ++ts) {
    const int bi = ts & 1;
    asm volatile("s_waitcnt vmcnt(0)" ::: "memory");   // STAGE2(ts) landed
    __builtin_amdgcn_s_barrier();                      // prev step's readers done
    __builtin_amdgcn_sched_barrier(0);
    if (ts + 1 < NTS) STAGE2(ts + 1);

    // ---- S^T for both tiles: 4 independent 4-deep MFMA chains ----
    f32x16 st[2][2];
    #pragma unroll
    for (int s = 0; s < 2; ++s)
      #pragma unroll
      for (int kt2 = 0; kt2 < 2; ++kt2)
        #pragma unroll
        for (int r = 0; r < 16; ++r) st[s][kt2][r] = 0.0f;
    __builtin_amdgcn_s_setprio(1);
    #pragma unroll
    for (int dk = 0; dk < 4; ++dk)
      #pragma unroll
      for (int s = 0; s < 2; ++s)
        #pragma unroll
        for (int kt2 = 0; kt2 < 2; ++kt2) {
          int krow = kt2 * 32 + q31;
          bf16x8 kfr = *(const bf16x8*)&Kl[bi][s][krow * 64 + (((2 * dk + hi) ^ (krow & 7)) * 8)];
          st[s][kt2] = __builtin_amdgcn_mfma_f32_32x32x16_bf16(kfr, qf[dk], st[s][kt2], 0, 0, 0);
        }
    __builtin_amdgcn_s_setprio(0);
    // ---- causal mask: tile kt >= ktmax (kt > ktmax wipes fully) ----
    #pragma unroll
    for (int s = 0; s < 2; ++s) {
      int kt = 2 * ts + s;
      if (kt >= ktmax) {
        #pragma unroll
        for (int kt2 = 0; kt2 < 2; ++kt2)
          #pragma unroll
          for (int r = 0; r < 16; ++r) {
            int kg = kt * 64 + kt2 * 32 + (r & 3) + 8 * (r >> 2) + 4 * hi;
            if (kg > qmy) st[s][kt2][r] = -1e30f;
          }
      }
    }
    // ---- online softmax over 128 cols, one sequence per step ----
    float m0[8];
    #pragma unroll
    for (int i = 0; i < 8; ++i)
      m0[i] = fmaxf(fmaxf(max3f(st[0][0][i], st[0][0][i + 8], st[0][1][i]),
                          max3f(st[0][1][i + 8], st[1][0][i], st[1][0][i + 8])),
                    fmaxf(st[1][1][i], st[1][1][i + 8]));
    float mt = max3f(max3f(m0[0], m0[1], m0[2]), max3f(m0[3], m0[4], m0[5]),
                     fmaxf(m0[6], m0[7]));
    if (__any((mt - m_) * cexp > 8.0f)) {   // defer-max (T13)
      float mg = fmaxf(mt, __shfl_xor(mt, 32, 64));
      float mn = fmaxf(m_, mg);
      float al = __builtin_amdgcn_exp2f((m_ - mn) * cexp);
      m_ = mn;
      la[0] *= al;
      #pragma unroll
      for (int dt = 0; dt < 2; ++dt)
        #pragma unroll
        for (int r = 0; r < 16; ++r) oa[dt][r] *= al;
    }
    const float mc = m_ * cexp;
    #pragma unroll
    for (int s = 0; s < 2; ++s)
      #pragma unroll
      for (int kt2 = 0; kt2 < 2; ++kt2)
        #pragma unroll
        for (int r = 0; r < 16; ++r)
          st[s][kt2][r] = __builtin_amdgcn_exp2f(fmaf(st[s][kt2][r], cexp, -mc));
    // ---- per tile: pack P, then PV + l on the matrix pipe ----
    #pragma unroll
    for (int s = 0; s < 2; ++s) {
      bf16x8 pfr[4];
      #pragma unroll
      for (int ks = 0; ks < 4; ++ks) {
        int tt = ks >> 1, gX = 2 * (ks & 1), gY = gX + 1;
        unsigned int x1 = cvtpk(st[s][tt][4 * gX + 0], st[s][tt][4 * gX + 1]);
        unsigned int y1 = cvtpk(st[s][tt][4 * gY + 0], st[s][tt][4 * gY + 1]);
        plswap(x1, y1);
        unsigned int x2 = cvtpk(st[s][tt][4 * gX + 2], st[s][tt][4 * gX + 3]);
        unsigned int y2 = cvtpk(st[s][tt][4 * gY + 2], st[s][tt][4 * gY + 3]);
        plswap(x2, y2);
        union { unsigned int u[4]; bf16x8 b; } cc;
        cc.u[0] = x1; cc.u[1] = x2; cc.u[2] = y1; cc.u[3] = y2;
        pfr[ks] = cc.b;
      }
      __builtin_amdgcn_s_setprio(1);
      #pragma unroll
      for (int ks = 0; ks < 4; ++ks) {
        la = __builtin_amdgcn_mfma_f32_32x32x16_bf16(onesf, pfr[ks], la, 0, 0, 0);
        #pragma unroll
        for (int dt = 0; dt < 2; ++dt) {
          int vrow = dt * 32 + q31;
          bf16x8 vf = *(const bf16x8*)&Vl[bi][s][vrow * 64 + (((2 * ks + hi) ^ (vrow & 7)) * 8)];
          oa[dt] = __builtin_amdgcn_mfma_f32_32x32x16_bf16(vf, pfr[ks], oa[dt], 0, 0, 0);
        }
      }
      __builtin_amdgcn_s_setprio(0);
    }
  }

  float inv = 1.0f / la[0];
  #pragma unroll
  for (int dt = 0; dt < 2; ++dt)
    #pragma unroll
    for (int g = 0; g < 4; ++g) {
      ushort4 o4;
      o4.x = f2bf(oa[dt][4 * g + 0] * inv);
      o4.y = f2bf(oa[dt][4 * g + 1] * inv);
      o4.z = f2bf(oa[dt][4 * g + 2] * inv);
      o4.w = f2bf(oa[dt][4 * g + 3] * inv);
      *(ushort4*)&O[qgrow * 1024 + h * 64 + dt * 32 + 8 * g + 4 * hi] = o4;
    }
}

// ---------------- launch ----------------
extern "C" void kernel_launch(void* const* d_in, const int* in_sizes, int n_in,
                              void* d_out, int out_size, void* d_ws, size_t ws_size,
                              hipStream_t stream) {
  const float* x  = (const float*)d_in[0];
  const float* Wq = (const float*)d_in[1];
  const float* Wk = (const float*)d_in[2];
  const float* Wv = (const float*)d_in[3];
  const float* Wo = (const float*)d_in[4];
  char* ws = (char*)d_ws;
  unsigned short* xb   = (unsigned short*)(ws);                    // 8 MiB (x bf16; later Vt)
  unsigned short* Wb   = (unsigned short*)(ws + (8u << 20));       // 6 MiB
  unsigned short* Wob  = (unsigned short*)(ws + (14u << 20));      // 2 MiB
  unsigned short* QKVb = (unsigned short*)(ws + (16u << 20));      // 24 MiB
  unsigned short* Ob   = (unsigned short*)(ws + (40u << 20));      // 8 MiB
  unsigned short* Vtg  = xb;                                       // reuse: x dead after QKV GEMM

  cvt_all<<<8192, 256, 0, stream>>>(x, Wq, Wk, Wv, Wo, xb, Wb, Wob);
  gemm_bt<0><<<dim3(32, 24), 256, 0, stream>>>(xb, Wb, QKVb, 3072, 1024);
  ropevtr_k<<<5120, 256, 0, stream>>>(QKVb, Vtg);
  attn_k<<<dim3(32, 16), 256, 0, stream>>>(QKVb, Vtg, Ob);
  gemm2_bt<<<dim3(64, 8), 128, 0, stream>>>(Ob, Wob, (float*)d_out, 1024, 1024);
}